// Round 6
// baseline (1192.262 us; speedup 1.0000x reference)
//
#include <hip/hip_runtime.h>
#include <hip/hip_bf16.h>

#define C 64  // channels

// bf16 <-> f32 helpers (bit-level, RNE on pack)
__device__ __forceinline__ float b2f(unsigned short s) {
    return __uint_as_float(((unsigned int)s) << 16);
}
__device__ __forceinline__ unsigned short f2b(float f) {
    unsigned int u = __float_as_uint(f);
    u = (u + 0x7FFF + ((u >> 16) & 1)) >> 16;
    return (unsigned short)u;
}

// ---------------------------------------------------------------------------
// Fused MLP: h = relu(relu(x @ W1) @ W2).
// Writes BOTH fp32 h0 (hop-0 gate) and bf16 hb (propagation seed).
// R6: LDS cut 34816->21760B so 7 blocks/CU (was 4): GEMM1 BK=32
// (As[64][36]+Bs[32][68]=17.9KB), GEMM2 stages W2 in 16-row k-chunks
// (Hs[64][68]+Ws[16][68]=21.3KB).  Grid 1563 blocks vs capacity 1792 ->
// single batch, no tail (R4/R5: capacity 1024 -> 53%-full second batch,
// Occupancy 32%, VALUBusy 48%).  Microtile/padding unchanged (0 conflicts
// measured through R5); VGPR 64 -> 28 waves/CU fits pool.
// ---------------------------------------------------------------------------
__launch_bounds__(256)
__global__ void mlp_kernel(const float* __restrict__ x,
                           const float* __restrict__ W1,
                           const float* __restrict__ W2,
                           float* __restrict__ h0,
                           unsigned short* __restrict__ hb, int nN)
{
    __shared__ float smem[5440];
    float (*As)[36] = (float(*)[36])smem;            // 64 x 36 = 2304
    float (*Bs)[68] = (float(*)[68])(smem + 2304);   // 32 x 68 = 2176
    float (*Hs)[68] = (float(*)[68])smem;            // 64 x 68 = 4352 (reuse)
    float (*Ws)[68] = (float(*)[68])(smem + 4352);   // 16 x 68 = 1088

    const int t  = threadIdx.x;
    const int ty = t >> 4;
    const int tx = t & 15;
    const int row0 = blockIdx.x * 64;

    float acc[4][4] = {};

    for (int k0 = 0; k0 < 512; k0 += 32) {
        #pragma unroll
        for (int h = 0; h < 2; ++h) {
            int f = t + 256 * h;
            int r  = f >> 3;
            int lk = (f & 7) * 4;
            int grow = row0 + r;
            float4 v = make_float4(0.f, 0.f, 0.f, 0.f);
            if (grow < nN) v = *(const float4*)&x[(size_t)grow * 512 + k0 + lk];
            *(float4*)&As[r][lk] = v;
        }
        #pragma unroll
        for (int h = 0; h < 2; ++h) {
            int f = t + 256 * h;
            int kr = f >> 4;
            int c4 = (f & 15) * 4;
            *(float4*)&Bs[kr][c4] = *(const float4*)&W1[(size_t)(k0 + kr) * 64 + c4];
        }
        __syncthreads();

        for (int kk = 0; kk < 32; kk += 4) {
            float4 b0 = *(float4*)&Bs[kk + 0][tx * 4];
            float4 b1 = *(float4*)&Bs[kk + 1][tx * 4];
            float4 b2 = *(float4*)&Bs[kk + 2][tx * 4];
            float4 b3 = *(float4*)&Bs[kk + 3][tx * 4];
            #pragma unroll
            for (int i = 0; i < 4; ++i) {
                float4 a = *(float4*)&As[ty * 4 + i][kk];
                acc[i][0] += a.x * b0.x + a.y * b1.x + a.z * b2.x + a.w * b3.x;
                acc[i][1] += a.x * b0.y + a.y * b1.y + a.z * b2.y + a.w * b3.y;
                acc[i][2] += a.x * b0.z + a.y * b1.z + a.z * b2.z + a.w * b3.z;
                acc[i][3] += a.x * b0.w + a.y * b1.w + a.z * b2.w + a.w * b3.w;
            }
        }
        __syncthreads();
    }

    // ReLU -> Hs (reuses As/Bs region; last barrier guarantees reads done)
    #pragma unroll
    for (int i = 0; i < 4; ++i) {
        float4 o;
        o.x = acc[i][0] > 0.f ? acc[i][0] : 0.f;
        o.y = acc[i][1] > 0.f ? acc[i][1] : 0.f;
        o.z = acc[i][2] > 0.f ? acc[i][2] : 0.f;
        o.w = acc[i][3] > 0.f ? acc[i][3] : 0.f;
        *(float4*)&Hs[ty * 4 + i][tx * 4] = o;
    }

    // GEMM2: h2 = relu(Hs @ W2), W2 staged 16 k-rows at a time
    float acc2[4][4] = {};
    for (int k0w = 0; k0w < 64; k0w += 16) {
        __syncthreads();   // Hs write (iter0) / previous chunk reads done
        {
            int r  = t >> 4;
            int c4 = (t & 15) * 4;
            *(float4*)&Ws[r][c4] = *(const float4*)&W2[(size_t)(k0w + r) * 64 + c4];
        }
        __syncthreads();

        for (int kk = 0; kk < 16; kk += 4) {
            float4 b0 = *(float4*)&Ws[kk + 0][tx * 4];
            float4 b1 = *(float4*)&Ws[kk + 1][tx * 4];
            float4 b2 = *(float4*)&Ws[kk + 2][tx * 4];
            float4 b3 = *(float4*)&Ws[kk + 3][tx * 4];
            #pragma unroll
            for (int i = 0; i < 4; ++i) {
                float4 a = *(float4*)&Hs[ty * 4 + i][k0w + kk];
                acc2[i][0] += a.x * b0.x + a.y * b1.x + a.z * b2.x + a.w * b3.x;
                acc2[i][1] += a.x * b0.y + a.y * b1.y + a.z * b2.y + a.w * b3.y;
                acc2[i][2] += a.x * b0.z + a.y * b1.z + a.z * b2.z + a.w * b3.z;
                acc2[i][3] += a.x * b0.w + a.y * b1.w + a.z * b2.w + a.w * b3.w;
            }
        }
    }

    #pragma unroll
    for (int i = 0; i < 4; ++i) {
        int grow = row0 + ty * 4 + i;
        if (grow < nN) {
            float4 o;
            o.x = acc2[i][0] > 0.f ? acc2[i][0] : 0.f;
            o.y = acc2[i][1] > 0.f ? acc2[i][1] : 0.f;
            o.z = acc2[i][2] > 0.f ? acc2[i][2] : 0.f;
            o.w = acc2[i][3] > 0.f ? acc2[i][3] : 0.f;
            *(float4*)&h0[(size_t)grow * 64 + tx * 4] = o;
            ushort4 ob = make_ushort4(f2b(o.x), f2b(o.y), f2b(o.z), f2b(o.w));
            *(ushort4*)&hb[(size_t)grow * 64 + tx * 4] = ob;
        }
    }
}

// ---------------------------------------------------------------------------
// CSR build: degree count -> hierarchical scan -> atomic fill.
// After fill, rowptr[n] = END offset; start = rowptr[n-1] (0 for n=0).
// ---------------------------------------------------------------------------
__launch_bounds__(256)
__global__ void count_kernel(const int* __restrict__ dst, int* __restrict__ rowptr, int nE)
{
    int e = blockIdx.x * 256 + threadIdx.x;
    if (e < nE) atomicAdd(&rowptr[dst[e]], 1);
}

// per-block exclusive scan of 1024 elements (256 thr x 4), block total -> bsum
__launch_bounds__(256)
__global__ void scanA(int* __restrict__ deg, int* __restrict__ bsum, int nN)
{
    __shared__ int ts[256];
    const int t = threadIdx.x;
    const int base = blockIdx.x * 1024 + t * 4;
    int v0 = 0, v1 = 0, v2 = 0, v3 = 0;
    if (base + 3 < nN) {
        int4 v = *(const int4*)&deg[base];
        v0 = v.x; v1 = v.y; v2 = v.z; v3 = v.w;
    } else {
        if (base + 0 < nN) v0 = deg[base + 0];
        if (base + 1 < nN) v1 = deg[base + 1];
        if (base + 2 < nN) v2 = deg[base + 2];
        if (base + 3 < nN) v3 = deg[base + 3];
    }
    int s = v0 + v1 + v2 + v3;
    ts[t] = s;
    __syncthreads();
    for (int d = 1; d < 256; d <<= 1) {
        int xv = (t >= d) ? ts[t - d] : 0;
        __syncthreads();
        ts[t] += xv;
        __syncthreads();
    }
    if (t == 255) bsum[blockIdx.x] = ts[255];
    int e0 = ts[t] - s;      // exclusive within block
    int e1 = e0 + v0;
    int e2 = e1 + v1;
    int e3 = e2 + v2;
    if (base + 3 < nN) {
        *(int4*)&deg[base] = make_int4(e0, e1, e2, e3);
    } else {
        if (base + 0 < nN) deg[base + 0] = e0;
        if (base + 1 < nN) deg[base + 1] = e1;
        if (base + 2 < nN) deg[base + 2] = e2;
        if (base + 3 < nN) deg[base + 3] = e3;
    }
}

// exclusive scan of up to 256 block sums, in place
__launch_bounds__(256)
__global__ void scanB(int* __restrict__ bsum, int nB)
{
    __shared__ int ts[256];
    const int t = threadIdx.x;
    int v = (t < nB) ? bsum[t] : 0;
    ts[t] = v;
    __syncthreads();
    for (int d = 1; d < 256; d <<= 1) {
        int xv = (t >= d) ? ts[t - d] : 0;
        __syncthreads();
        ts[t] += xv;
        __syncthreads();
    }
    if (t < nB) bsum[t] = ts[t] - v;
}

// add scanned block sums back
__launch_bounds__(256)
__global__ void scanC(int* __restrict__ deg, const int* __restrict__ bsum, int nN)
{
    const int i4 = (blockIdx.x * 256 + threadIdx.x) * 4;
    if (i4 >= nN) return;
    const int b = bsum[i4 >> 10];
    if (i4 + 3 < nN) {
        int4 v = *(int4*)&deg[i4];
        v.x += b; v.y += b; v.z += b; v.w += b;
        *(int4*)&deg[i4] = v;
    } else {
        for (int j = 0; j < 4 && i4 + j < nN; ++j) deg[i4 + j] += b;
    }
}

__launch_bounds__(256)
__global__ void fill_kernel(const int* __restrict__ src, const int* __restrict__ dst,
                            const float* __restrict__ w,
                            int* __restrict__ rowptr,
                            int2* __restrict__ cwp, int nE)
{
    int e = blockIdx.x * 256 + threadIdx.x;
    if (e >= nE) return;
    int d = dst[e];
    int pos = atomicAdd(&rowptr[d], 1);
    cwp[pos] = make_int2(src[e], __float_as_int(w[e]));
}

// ---------------------------------------------------------------------------
// Fused pull-SpMM + gate, bf16 propagation.  One wave per dst node (or per
// output index).  8 edge sub-slots x 8 lanes x int4 (16B = 8 bf16 ch/lane).
// R6: direct BROADCAST cwp loads (cwp[e+g], 8 lanes/address, 64B/instr)
// replace the coalesced-load -> wait -> shfl -> gather chain: one fewer
// cross-lane dependency per 16 edges, no chunk/rem bookkeeping, and each
// iteration's load chain is independent (scheduler can overlap).
// OOB slots carry w=0, col=0 (harmless row-0 gather); no tail loop.
// ---------------------------------------------------------------------------
__launch_bounds__(256)
__global__ void spmm_fused(const int* __restrict__ rowptr,
                           const int2* __restrict__ cwp,
                           const unsigned short* __restrict__ cur,
                           unsigned short* __restrict__ nxt,
                           const int* __restrict__ idx,
                           const float* __restrict__ wp,
                           float* __restrict__ out,
                           int nN, int nI, int nodeBlocks)
{
    const int bid  = blockIdx.x;
    const int wid  = threadIdx.x >> 6;
    const int lane = threadIdx.x & 63;
    const int g = lane >> 3;   // edge sub-slot 0..7
    const int q = lane & 7;    // channel octet (8 bf16 = 16B)

    int node, oi = -1;
    if (bid < nodeBlocks) {
        node = bid * 4 + wid;
        if (node >= nN) return;
    } else {
        oi = (bid - nodeBlocks) * 4 + wid;
        if (oi >= nI) return;
        node = idx[oi];
    }

    const int beg = (node == 0) ? 0 : rowptr[node - 1];
    const int end = rowptr[node];

    float a0[8] = {}, a1[8] = {};

    for (int e = beg; e < end; e += 16) {
        int ea = e + g;
        int eb = ea + 8;
        int2 ca = (ea < end) ? cwp[ea] : make_int2(0, 0);
        int2 cb = (eb < end) ? cwp[eb] : make_int2(0, 0);
        float wa = __int_as_float(ca.y);
        float wb = __int_as_float(cb.y);
        int4 ra = *(const int4*)&cur[(size_t)ca.x * 64 + q * 8];
        int4 rb = *(const int4*)&cur[(size_t)cb.x * 64 + q * 8];
        a0[0] += wa * __uint_as_float((unsigned)ra.x << 16);
        a0[1] += wa * __uint_as_float((unsigned)ra.x & 0xFFFF0000u);
        a0[2] += wa * __uint_as_float((unsigned)ra.y << 16);
        a0[3] += wa * __uint_as_float((unsigned)ra.y & 0xFFFF0000u);
        a0[4] += wa * __uint_as_float((unsigned)ra.z << 16);
        a0[5] += wa * __uint_as_float((unsigned)ra.z & 0xFFFF0000u);
        a0[6] += wa * __uint_as_float((unsigned)ra.w << 16);
        a0[7] += wa * __uint_as_float((unsigned)ra.w & 0xFFFF0000u);
        a1[0] += wb * __uint_as_float((unsigned)rb.x << 16);
        a1[1] += wb * __uint_as_float((unsigned)rb.x & 0xFFFF0000u);
        a1[2] += wb * __uint_as_float((unsigned)rb.y << 16);
        a1[3] += wb * __uint_as_float((unsigned)rb.y & 0xFFFF0000u);
        a1[4] += wb * __uint_as_float((unsigned)rb.z << 16);
        a1[5] += wb * __uint_as_float((unsigned)rb.z & 0xFFFF0000u);
        a1[6] += wb * __uint_as_float((unsigned)rb.w << 16);
        a1[7] += wb * __uint_as_float((unsigned)rb.w & 0xFFFF0000u);
    }
    #pragma unroll
    for (int j = 0; j < 8; ++j) a0[j] += a1[j];

    // reduce across the 8 edge sub-slots (lane bits 3,4,5)
    #pragma unroll
    for (int j = 0; j < 8; ++j) {
        a0[j] += __shfl_xor(a0[j], 8);
        a0[j] += __shfl_xor(a0[j], 16);
        a0[j] += __shfl_xor(a0[j], 32);
    }

    if (oi < 0) {
        if (g == 0) {
            int4 ob;
            ob.x = (int)(((unsigned)f2b(a0[1]) << 16) | (unsigned)f2b(a0[0]));
            ob.y = (int)(((unsigned)f2b(a0[3]) << 16) | (unsigned)f2b(a0[2]));
            ob.z = (int)(((unsigned)f2b(a0[5]) << 16) | (unsigned)f2b(a0[4]));
            ob.w = (int)(((unsigned)f2b(a0[7]) << 16) | (unsigned)f2b(a0[6]));
            *(int4*)&nxt[(size_t)node * 64 + q * 8] = ob;
        }
    } else {
        // gate: s = row . wp  (partial dot over this lane's 8 ch, then
        // reduce across the 8 q-lanes = lane bits 0,1,2)
        float s = 0.f;
        #pragma unroll
        for (int j = 0; j < 8; ++j) s += a0[j] * wp[q * 8 + j];
        s += __shfl_xor(s, 1); s += __shfl_xor(s, 2); s += __shfl_xor(s, 4);
        float gate = 1.f / (1.f + __expf(-s));
        if (g == 0) {
            float* op = &out[(size_t)oi * 64 + q * 8];
            float4 p0 = *(float4*)op;
            float4 p1 = *(float4*)(op + 4);
            p0.x += gate * a0[0]; p0.y += gate * a0[1];
            p0.z += gate * a0[2]; p0.w += gate * a0[3];
            p1.x += gate * a0[4]; p1.y += gate * a0[5];
            p1.z += gate * a0[6]; p1.w += gate * a0[7];
            *(float4*)op = p0;
            *(float4*)(op + 4) = p1;
        }
    }
}

// ---------------------------------------------------------------------------
// Hop-0 gate: out[i] = sigmoid(h[idx[i]].wp) * h[idx[i]]  (fp32 h, inits out)
// ---------------------------------------------------------------------------
__launch_bounds__(256)
__global__ void gate_gather(const float* __restrict__ h,
                            const int* __restrict__ idx,
                            const float* __restrict__ wp,
                            float* __restrict__ out, int nI)
{
    int gid = blockIdx.x * 256 + threadIdx.x;
    int i = gid >> 6;
    if (i >= nI) return;
    int c = gid & 63;
    int n = idx[i];
    float v = h[(size_t)n * 64 + c];
    float s = v * wp[c];
    #pragma unroll
    for (int off = 32; off > 0; off >>= 1)
        s += __shfl_xor(s, off);
    float gate = 1.f / (1.f + __expf(-s));
    out[gid] = gate * v;
}

extern "C" void kernel_launch(void* const* d_in, const int* in_sizes, int n_in,
                              void* d_out, int out_size, void* d_ws, size_t ws_size,
                              hipStream_t stream) {
    const float* x    = (const float*)d_in[0];
    const int*   esrc = (const int*)d_in[1];
    const int*   edst = (const int*)d_in[2];
    const float* ew   = (const float*)d_in[3];
    const int*   nidx = (const int*)d_in[4];
    const float* W1   = (const float*)d_in[5];
    const float* W2   = (const float*)d_in[6];
    const float* wp   = (const float*)d_in[7];
    float* out = (float*)d_out;

    const int nN = in_sizes[0] / 512;
    const int nE = in_sizes[1];
    const int nI = in_sizes[4];

    // ws: h0 fp32 25.6M | bufA bf16 12.8M | bufB bf16 12.8M | rowptr 0.4M | cwp 12.8M
    float*          h0     = (float*)d_ws;
    unsigned short* bufA   = (unsigned short*)(h0 + (size_t)nN * C);
    unsigned short* bufB   = bufA + (size_t)nN * C;
    int*            rowptr = (int*)(bufB + (size_t)nN * C);
    int2*           cwp    = (int2*)(rowptr + nN);
    // block sums for the hierarchical scan: bufB is dead until the first
    // spmm writes nxt, so borrow its head as scratch.
    int*            bsum   = (int*)bufB;

    const int nB = (nN + 1023) / 1024;   // <= 256 for nN <= 262144

    // --- CSR build (by dst) ---
    hipMemsetAsync(rowptr, 0, (size_t)nN * sizeof(int), stream);
    count_kernel<<<(nE + 255) / 256, 256, 0, stream>>>(edst, rowptr, nE);
    scanA<<<nB, 256, 0, stream>>>(rowptr, bsum, nN);
    scanB<<<1, 256, 0, stream>>>(bsum, nB);
    scanC<<<nB, 256, 0, stream>>>(rowptr, bsum, nN);
    fill_kernel<<<(nE + 255) / 256, 256, 0, stream>>>(esrc, edst, ew, rowptr, cwp, nE);

    // --- MLP (fp32 + bf16 h) ---
    mlp_kernel<<<(nN + 63) / 64, 256, 0, stream>>>(x, W1, W2, h0, bufA, nN);

    // hop 0 gate (initializes out, fp32 path)
    gate_gather<<<(nI * 64 + 255) / 256, 256, 0, stream>>>(h0, nidx, wp, out, nI);

    unsigned short* cur = bufA;
    unsigned short* nxt = bufB;
    const int nodeBlocks = (nN + 3) / 4;
    const int idxBlocks  = (nI + 3) / 4;
    for (int k = 0; k < 10; ++k) {
        // Final hop: nxt is never read again -> launch only the idx-tail
        // blocks (gate into out); skip the 25k node blocks entirely.
        const int nb = (k == 9) ? 0 : nodeBlocks;
        spmm_fused<<<nb + idxBlocks, 256, 0, stream>>>(
            rowptr, cwp, cur, nxt, nidx, wp, out, nN, nI, nb);
        unsigned short* tmp = cur; cur = nxt; nxt = tmp;
    }
}